// Round 1
// baseline (232.013 us; speedup 1.0000x reference)
//
#include <hip/hip_runtime.h>

#define NFEAT 5
#define KDIM  80
#define NTH   16
#define NRHO  5
#define NROT  16
#define VCNT  200
#define EPSF  1e-5f

#define DTH     0.39269908169872414f   /* 2*pi/16 */
#define INV_DTH 2.5464790894703254f    /* 16/(2*pi) */

/* LDS float offsets */
#define OFF_PERVX 0        /* [200][12]: f0..f4, grm0..grm4, iv, pad */
#define OFF_GVALS 2400     /* [200][33]: theta-gauss table (31 used) */
#define OFF_DESCN 9000     /* [16][80*5]: normalized descriptors      */
#define OFF_SCR   15400    /* [8][16][36]: reduction scratch          */
#define SMEM_F    20008    /* 80032 bytes */

__global__ __launch_bounds__(256, 2)
void masif_fused(const float* __restrict__ feat, const float* __restrict__ rho,
                 const float* __restrict__ theta, const float* __restrict__ mask,
                 const float* __restrict__ mu_rho_p,
                 const float* __restrict__ sigma_rho_p,
                 const float* __restrict__ sigma_theta_p,
                 const float* __restrict__ Wc, const float* __restrict__ bc,
                 const float* __restrict__ W1, const float* __restrict__ b1,
                 const float* __restrict__ W2, const float* __restrict__ b2,
                 float* __restrict__ out, int nB)
{
  __shared__ __align__(16) float smem[SMEM_F];
  float* pervx = smem + OFF_PERVX;
  float* gvals = smem + OFF_GVALS;
  float* descn = smem + OFF_DESCN;
  float* scr   = smem + OFF_SCR;

  const int b = blockIdx.x;
  if (b >= nB) return;
  const int tid  = threadIdx.x;
  const int lane = tid & 63;
  const int wv   = tid >> 6;
  const int g    = tid >> 4;   /* v-group 0..15 */
  const int t    = tid & 15;   /* theta index 0..15 */

  /* ---------------- prologue: per-vertex tables ---------------- */
  if (tid < VCNT) {
    const int v = tid;
    const size_t base = (size_t)b * VCNT + v;
    const float rh = rho[base];
    const float m  = mask[base];
    const float th = theta[base];
    const float sr = sigma_rho_p[0];
    const float st = sigma_theta_p[0];
    const float isr = 1.0f / (sr*sr + EPSF);
    const float ist = 1.0f / (st*st + EPSF);
    float* px = pervx + v*12;
    #pragma unroll
    for (int j = 0; j < NFEAT; ++j) px[j] = feat[base*NFEAT + j];
    #pragma unroll
    for (int r = 0; r < NRHO; ++r) {
      const float d = rh - mu_rho_p[r*NTH];
      px[5+r] = expf(-d*d*isr) * m;   /* rho-gauss * mask */
    }
    const float u  = th * INV_DTH;
    const int   iv = (int)u;
    const float fv = u - (float)iv;
    px[10] = (float)iv;
    px[11] = 0.0f;
    float* gvr = gvals + v*33;
    #pragma unroll
    for (int mi = 0; mi < 31; ++mi) {
      const float d = DTH * ((float)(mi - 15) + fv);
      gvr[mi] = expf(-d*d*ist);
    }
    gvr[31] = 0.0f; gvr[32] = 0.0f;
  }
  __syncthreads();

  /* ---------------- rotation loop: 4 tiles x 4 rots ---------------- */
  #pragma unroll 1
  for (int tile = 0; tile < 4; ++tile) {
    float acc[4][30];
    #pragma unroll
    for (int q = 0; q < 4; ++q)
      #pragma unroll
      for (int c = 0; c < 30; ++c) acc[q][c] = 0.0f;

    for (int v = g; v < VCNT; v += 16) {
      const float4 pa  = *(const float4*)(pervx + v*12 + 0);
      const float4 pb  = *(const float4*)(pervx + v*12 + 4);
      const float4 pc4 = *(const float4*)(pervx + v*12 + 8);
      const float fj[5] = {pa.x, pa.y, pa.z, pa.w, pb.x};
      const float gr[5] = {pb.y, pb.z, pb.w, pc4.x, pc4.y};
      const int   iv    = (int)pc4.z;
      const float* gvr  = gvals + v*33 + (15 - t);
      #pragma unroll
      for (int q = 0; q < 4; ++q) {
        const int kf = tile*4 + q;
        const int c  = (iv + kf) & 15;
        const float gth = gvr[c];
        #pragma unroll
        for (int r = 0; r < 5; ++r) {
          const float p = gr[r] * gth;
          acc[q][r*6] += p;                       /* S   */
          #pragma unroll
          for (int j = 0; j < 5; ++j)
            acc[q][r*6+1+j] += p * fj[j];         /* desc */
        }
      }
    }

    /* pair-reduce over g ^ 2 (lane xor 32) -> 8 partial sets */
    #pragma unroll
    for (int q = 0; q < 4; ++q)
      #pragma unroll
      for (int c = 0; c < 30; ++c)
        acc[q][c] += __shfl_xor(acc[q][c], 32);

    #pragma unroll
    for (int q = 0; q < 4; ++q) {
      __syncthreads();                 /* prev rot's reads done */
      if (lane < 32) {
        const int p = wv*2 + (lane >> 4);
        float* srow = scr + (p*16 + t)*36;
        #pragma unroll
        for (int c0 = 0; c0 < 28; c0 += 4)
          *(float4*)(srow + c0) =
            make_float4(acc[q][c0], acc[q][c0+1], acc[q][c0+2], acc[q][c0+3]);
        srow[28] = acc[q][28];
        srow[29] = acc[q][29];
      }
      __syncthreads();
      if (tid < KDIM) {
        const int rr = tid >> 4, tt = tid & 15;
        float s0=0.f,s1=0.f,s2=0.f,s3=0.f,s4=0.f,s5=0.f;
        #pragma unroll
        for (int p = 0; p < 8; ++p) {
          const float* srow = scr + (p*16 + tt)*36 + rr*6;
          s0 += srow[0]; s1 += srow[1]; s2 += srow[2];
          s3 += srow[3]; s4 += srow[4]; s5 += srow[5];
        }
        const float inv = 1.0f / (s0 + EPSF);
        float* dn = descn + (tile*4 + q)*400 + tid*5;
        dn[0] = s1*inv; dn[1] = s2*inv; dn[2] = s3*inv;
        dn[3] = s4*inv; dn[4] = s5*inv;
      }
    }
  }
  __syncthreads();

  /* ---------------- zero ret (reuse dead pervx region) ---------------- */
  int* reti = (int*)smem;              /* ret[400] as float-bits */
  for (int o = tid; o < 400; o += 256) reti[o] = 0;
  __syncthreads();

  /* ---------------- conv (desc @ W + b), max over rots, relu ---------------- */
  if (tid < 200) {
    const int ic  = tid / 40;          /* feature 0..4   */
    const int rem = tid % 40;
    const int kfg = rem / 10;          /* rot-quad 0..3  */
    const int kg  = rem % 10;          /* k-octet 0..9   */
    float a2[4][8];
    #pragma unroll
    for (int q = 0; q < 4; ++q)
      #pragma unroll
      for (int kk = 0; kk < 8; ++kk) a2[q][kk] = 0.0f;

    const float* wb = Wc + (size_t)ic*6400 + kg*8;
    #pragma unroll 2
    for (int kp = 0; kp < 80; ++kp) {
      const float4 w0 = *(const float4*)(wb + kp*80);
      const float4 w1 = *(const float4*)(wb + kp*80 + 4);
      const float w8[8] = {w0.x,w0.y,w0.z,w0.w, w1.x,w1.y,w1.z,w1.w};
      #pragma unroll
      for (int q = 0; q < 4; ++q) {
        const float d = descn[(kfg*4 + q)*400 + kp*5 + ic];
        #pragma unroll
        for (int kk = 0; kk < 8; ++kk) a2[q][kk] += d * w8[kk];
      }
    }
    #pragma unroll
    for (int kk = 0; kk < 8; ++kk) {
      float mx = fmaxf(fmaxf(a2[0][kk], a2[1][kk]), fmaxf(a2[2][kk], a2[3][kk]));
      const int k = kg*8 + kk;
      mx += bc[ic*KDIM + k];
      mx = fmaxf(mx, 0.0f);
      atomicMax(&reti[k*NFEAT + ic], __float_as_int(mx));
    }
  }
  __syncthreads();

  /* ---------------- FC1 (400->80) ---------------- */
  float* retf = (float*)reti;          /* non-negative floats */
  float* ret1 = smem + 416;            /* 80 floats, still inside dead pervx */
  if (tid < KDIM) {
    float s = b1[tid];
    #pragma unroll 4
    for (int o = 0; o < 400; o += 4) {
      const float4 r4 = *(const float4*)(retf + o);
      s += r4.x * W1[(o+0)*KDIM + tid];
      s += r4.y * W1[(o+1)*KDIM + tid];
      s += r4.z * W1[(o+2)*KDIM + tid];
      s += r4.w * W1[(o+3)*KDIM + tid];
    }
    ret1[tid] = fmaxf(s, 0.0f);
  }
  __syncthreads();

  /* ---------------- FC2 (80->5) ---------------- */
  if (tid < NFEAT) {
    float s = b2[tid];
    #pragma unroll 8
    for (int k2 = 0; k2 < KDIM; ++k2)
      s += ret1[k2] * W2[k2*NFEAT + tid];
    out[(size_t)b*NFEAT + tid] = fmaxf(s, 0.0f);
  }
}

extern "C" void kernel_launch(void* const* d_in, const int* in_sizes, int n_in,
                              void* d_out, int out_size, void* d_ws, size_t ws_size,
                              hipStream_t stream) {
  const float* feat    = (const float*)d_in[0];
  const float* rho     = (const float*)d_in[1];
  const float* theta   = (const float*)d_in[2];
  const float* mask    = (const float*)d_in[3];
  const float* mu_rho  = (const float*)d_in[4];
  /* d_in[5] = mu_theta: implied by the separable grid, not needed */
  const float* sig_rho = (const float*)d_in[6];
  const float* sig_th  = (const float*)d_in[7];
  const float* Wc      = (const float*)d_in[8];
  const float* bc      = (const float*)d_in[9];
  const float* W1      = (const float*)d_in[10];
  const float* b1      = (const float*)d_in[11];
  const float* W2      = (const float*)d_in[12];
  const float* b2      = (const float*)d_in[13];
  float* outp          = (float*)d_out;

  const int nB = in_sizes[1] / VCNT;   /* 2048 */
  masif_fused<<<dim3(nB), dim3(256), 0, stream>>>(
      feat, rho, theta, mask, mu_rho, sig_rho, sig_th,
      Wc, bc, W1, b1, W2, b2, outp, nB);
}

// Round 2
// 130.108 us; speedup vs baseline: 1.7832x; 1.7832x over previous
//
#include <hip/hip_runtime.h>

#define NFEAT 5
#define KDIM  80
#define NTH   16
#define NRHO  5
#define NROT  16
#define VCNT  200
#define EPSF  1e-5f

#define DTH     0.39269908169872414f   /* 2*pi/16 */
#define INV_DTH 2.5464790894703254f    /* 16/(2*pi) */

#define LDS_F 16384                    /* 64 KB */

__global__ __launch_bounds__(256, 2)
void masif_fused(const float* __restrict__ feat, const float* __restrict__ rho,
                 const float* __restrict__ theta, const float* __restrict__ mask,
                 const float* __restrict__ mu_rho_p,
                 const float* __restrict__ sigma_rho_p,
                 const float* __restrict__ sigma_theta_p,
                 const float* __restrict__ Wc, const float* __restrict__ bc,
                 const float* __restrict__ W1, const float* __restrict__ b1,
                 const float* __restrict__ W2, const float* __restrict__ b2,
                 float* __restrict__ out, int nB)
{
  __shared__ __align__(16) float smem[LDS_F];
  int*   ivs    = (int*)smem;          /* [200]           */
  int*   counts = (int*)smem + 208;    /* [16]            */
  int*   basep  = (int*)smem + 224;    /* [17]            */
  float* pv     = smem + 256;          /* [200][12] sorted: f0..4, gr0..4, pad */
  float* Gtab   = smem + 2656;         /* [200][33] sorted theta-gauss tables  */

  const int b = blockIdx.x;
  if (b >= nB) return;
  const int tid = threadIdx.x;

  if (tid < 16) counts[tid] = 0;

  int   my_iv = 0, my_rank = 0;
  float my_fv = 0.f, ist = 0.f;
  float myf[5], mygr[5];

  /* ---------- prologue: per-vertex quantities (regs) ---------- */
  if (tid < VCNT) {
    const size_t gbase = (size_t)b * VCNT + tid;
    const float rh = rho[gbase];
    const float mk = mask[gbase];
    const float th = theta[gbase];
    const float sr = sigma_rho_p[0];
    const float st = sigma_theta_p[0];
    const float isr = 1.0f / (sr*sr + EPSF);
    ist = 1.0f / (st*st + EPSF);
    const float u = th * INV_DTH;
    int iv = (int)u;
    iv = iv > 15 ? 15 : iv;
    my_iv = iv;
    my_fv = u - (float)iv;
    ivs[tid] = iv;
    #pragma unroll
    for (int j = 0; j < NFEAT; ++j) myf[j] = feat[gbase*NFEAT + j];
    #pragma unroll
    for (int r = 0; r < NRHO; ++r) {
      const float d = rh - mu_rho_p[r*NTH];
      mygr[r] = expf(-d*d*isr) * mk;   /* rho-gauss * mask */
    }
  }
  __syncthreads();

  /* ---------- deterministic rank-sort by theta-bin iv ---------- */
  if (tid < VCNT) {
    int rk = 0, tot = 0;
    #pragma unroll 8
    for (int w = 0; w < VCNT; ++w) {
      const int e = (ivs[w] == my_iv) ? 1 : 0;
      tot += e;
      rk  += e & (int)(w < tid);
    }
    my_rank = rk;
    if (rk == tot - 1) counts[my_iv] = tot;
  }
  __syncthreads();
  if (tid == 0) {
    int s = 0;
    #pragma unroll
    for (int i = 0; i < 16; ++i) { basep[i] = s; s += counts[i]; }
    basep[16] = s;
  }
  __syncthreads();

  /* ---------- write sorted per-vertex tables ---------- */
  if (tid < VCNT) {
    const int p = basep[my_iv] + my_rank;
    float* pvr = pv + p*12;
    pvr[0]=myf[0];  pvr[1]=myf[1];  pvr[2]=myf[2];  pvr[3]=myf[3];  pvr[4]=myf[4];
    pvr[5]=mygr[0]; pvr[6]=mygr[1]; pvr[7]=mygr[2]; pvr[8]=mygr[3]; pvr[9]=mygr[4];
    pvr[10]=0.f; pvr[11]=0.f;
    float* gt = Gtab + p*33;
    #pragma unroll
    for (int m = 0; m < 31; ++m) {
      const float d = DTH * ((float)(m - 15) + my_fv);
      gt[m] = expf(-d*d*ist);
    }
    gt[31] = 0.f; gt[32] = 0.f;
  }
  __syncthreads();

  /* ---------- phase P: binned accumulation in registers ----------
     thread (g=bin, q): owns m = q and q+16; acc[h][c], c = r*6+j (j=5 -> S) */
  const int g = tid >> 4;
  const int q = tid & 15;
  float acc[2][32];
  #pragma unroll
  for (int h = 0; h < 2; ++h)
    #pragma unroll
    for (int c = 0; c < 32; ++c) acc[h][c] = 0.f;

  {
    const int p0 = basep[g], p1 = basep[g+1];
    for (int p = p0; p < p1; ++p) {
      const float4 x0 = *(const float4*)(pv + p*12);
      const float4 x1 = *(const float4*)(pv + p*12 + 4);
      const float4 x2 = *(const float4*)(pv + p*12 + 8);
      const float f0=x0.x, f1=x0.y, f2=x0.z, f3=x0.w, f4=x1.x;
      const float gr[5] = {x1.y, x1.z, x1.w, x2.x, x2.y};
      const float G1 = Gtab[p*33 + q];
      const float G2 = Gtab[p*33 + q + 16];   /* q=15 -> slot 31 == 0 */
      #pragma unroll
      for (int r = 0; r < 5; ++r) {
        const float pa = gr[r]*G1;
        const float pb = gr[r]*G2;
        acc[0][r*6+0] += pa*f0; acc[0][r*6+1] += pa*f1; acc[0][r*6+2] += pa*f2;
        acc[0][r*6+3] += pa*f3; acc[0][r*6+4] += pa*f4; acc[0][r*6+5] += pa;
        acc[1][r*6+0] += pb*f0; acc[1][r*6+1] += pb*f1; acc[1][r*6+2] += pb*f2;
        acc[1][r*6+3] += pb*f3; acc[1][r*6+4] += pb*f4; acc[1][r*6+5] += pb;
      }
    }
  }
  __syncthreads();   /* prologue region dead; dump P over it */

  /* ---------- dump P[16][32][32] with chunk XOR-swizzle ---------- */
  #pragma unroll
  for (int h = 0; h < 2; ++h) {
    const int m = q + h*16;
    float* Pr = smem + (g*32 + m)*32;
    #pragma unroll
    for (int ch = 0; ch < 8; ++ch) {
      const int cc = ch ^ (m & 7);
      *(float4*)(Pr + cc*4) =
        make_float4(acc[h][ch*4], acc[h][ch*4+1], acc[h][ch*4+2], acc[h][ch*4+3]);
    }
  }
  __syncthreads();

  /* ---------- gather over bins + normalize (thread = (kf,t)) ---------- */
  const int kf = tid >> 4;
  const int tt = tid & 15;
  float sums[32];
  #pragma unroll
  for (int c = 0; c < 32; ++c) sums[c] = 0.f;
  #pragma unroll
  for (int i = 0; i < 16; ++i) {
    const int cp = (i + kf) & 15;
    const int m  = cp - tt + 15;          /* in [0,30] */
    const float* Pr = smem + (i*32 + m)*32;
    #pragma unroll
    for (int ch = 0; ch < 8; ++ch) {
      const int cc = ch ^ (m & 7);
      const float4 x = *(const float4*)(Pr + cc*4);
      sums[ch*4+0] += x.x; sums[ch*4+1] += x.y;
      sums[ch*4+2] += x.z; sums[ch*4+3] += x.w;
    }
  }
  float dsc[5][5];
  #pragma unroll
  for (int r = 0; r < 5; ++r) {
    const float inv = 1.0f / (sums[r*6+5] + EPSF);
    #pragma unroll
    for (int j = 0; j < 5; ++j) dsc[r][j] = sums[r*6+j] * inv;
  }
  __syncthreads();   /* P dead */

  /* ---------- write descn[16][400], zero ret ---------- */
  float* descn = smem;                 /* [16][400]  */
  int*   reti  = (int*)smem + 6400;    /* [400]      */
  #pragma unroll
  for (int r = 0; r < 5; ++r)
    #pragma unroll
    for (int j = 0; j < 5; ++j)
      descn[kf*400 + (r*16 + tt)*5 + j] = dsc[r][j];
  reti[tid] = 0;
  if (tid < 144) reti[256 + tid] = 0;
  __syncthreads();

  /* ---------- conv (desc @ W + b), max over rots, relu ---------- */
  if (tid < 200) {
    const int ic  = tid / 40;
    const int rem = tid % 40;
    const int kfg = rem / 10;
    const int kg  = rem % 10;
    float a2[4][8];
    #pragma unroll
    for (int qq = 0; qq < 4; ++qq)
      #pragma unroll
      for (int kk = 0; kk < 8; ++kk) a2[qq][kk] = 0.f;
    const float* wb = Wc + (size_t)ic*6400 + kg*8;
    #pragma unroll 2
    for (int kp = 0; kp < 80; ++kp) {
      const float4 w0 = *(const float4*)(wb + kp*80);
      const float4 w1 = *(const float4*)(wb + kp*80 + 4);
      const float w8[8] = {w0.x,w0.y,w0.z,w0.w, w1.x,w1.y,w1.z,w1.w};
      #pragma unroll
      for (int qq = 0; qq < 4; ++qq) {
        const float d = descn[(kfg*4 + qq)*400 + kp*5 + ic];
        #pragma unroll
        for (int kk = 0; kk < 8; ++kk) a2[qq][kk] += d * w8[kk];
      }
    }
    #pragma unroll
    for (int kk = 0; kk < 8; ++kk) {
      float mx = fmaxf(fmaxf(a2[0][kk], a2[1][kk]), fmaxf(a2[2][kk], a2[3][kk]));
      const int k = kg*8 + kk;
      mx += bc[ic*KDIM + k];
      mx = fmaxf(mx, 0.0f);
      atomicMax(&reti[k*NFEAT + ic], __float_as_int(mx));
    }
  }
  __syncthreads();

  /* ---------- FC1 (400->80) ---------- */
  float* retf = (float*)reti;
  float* ret1 = smem + 6800;
  if (tid < KDIM) {
    float s = b1[tid];
    #pragma unroll 4
    for (int o = 0; o < 400; o += 4) {
      const float4 r4 = *(const float4*)(retf + o);
      s += r4.x * W1[(o+0)*KDIM + tid];
      s += r4.y * W1[(o+1)*KDIM + tid];
      s += r4.z * W1[(o+2)*KDIM + tid];
      s += r4.w * W1[(o+3)*KDIM + tid];
    }
    ret1[tid] = fmaxf(s, 0.0f);
  }
  __syncthreads();

  /* ---------- FC2 (80->5) ---------- */
  if (tid < NFEAT) {
    float s = b2[tid];
    #pragma unroll 8
    for (int k2 = 0; k2 < KDIM; ++k2)
      s += ret1[k2] * W2[k2*NFEAT + tid];
    out[(size_t)b*NFEAT + tid] = fmaxf(s, 0.0f);
  }
}

extern "C" void kernel_launch(void* const* d_in, const int* in_sizes, int n_in,
                              void* d_out, int out_size, void* d_ws, size_t ws_size,
                              hipStream_t stream) {
  const float* feat    = (const float*)d_in[0];
  const float* rho     = (const float*)d_in[1];
  const float* theta   = (const float*)d_in[2];
  const float* mask    = (const float*)d_in[3];
  const float* mu_rho  = (const float*)d_in[4];
  /* d_in[5] = mu_theta: implied by the separable grid */
  const float* sig_rho = (const float*)d_in[6];
  const float* sig_th  = (const float*)d_in[7];
  const float* Wc      = (const float*)d_in[8];
  const float* bc      = (const float*)d_in[9];
  const float* W1      = (const float*)d_in[10];
  const float* b1      = (const float*)d_in[11];
  const float* W2      = (const float*)d_in[12];
  const float* b2      = (const float*)d_in[13];
  float* outp          = (float*)d_out;

  const int nB = in_sizes[1] / VCNT;   /* 2048 */
  masif_fused<<<dim3(nB), dim3(256), 0, stream>>>(
      feat, rho, theta, mask, mu_rho, sig_rho, sig_th,
      Wc, bc, W1, b1, W2, b2, outp, nB);
}